// Round 4
// baseline (435.315 us; speedup 1.0000x reference)
//
#include <hip/hip_runtime.h>

#define CUTOFF_F 5.2f

typedef float f4 __attribute__((ext_vector_type(4)));

// swizzle: lane pattern j0+4l (l=8m+r) -> bank 4r+m  => 2-way (free)
__device__ __forceinline__ int swz(int a) { return a + (a >> 5); }

#define NMAX 2048
#define SWZ_SZ (NMAX + (NMAX >> 5))   // 2112 floats per component

// Each thread handles 4 consecutive pairs of one batch's triangular pair list.
// Batch coords staged in LDS (SoA, swizzled); species==-1 folded into NaN coords.
// Output layout (float32):
//   [0,   P) idx0 (-1 if invalid)   [P,  2P) idx1
//   [2P, 3P) dist (0 if invalid)    [3P, 6P) diff[P][3]
__global__ __launch_bounds__(256) void AllPairs_kernel(
    const int* __restrict__ species,
    const float* __restrict__ coords,
    float* __restrict__ out,
    int N, int Psingle, int Ptotal)
{
    __shared__ float l3[3][SWZ_SZ];   // 25,344 B -> 6 blocks/CU (24 waves)

    const int b = blockIdx.y;
    const int baseAtom = b * N;

    // Stage this batch's coords into LDS SoA. Coalesced global reads (all
    // L2-resident after first block). Dummy atoms (species==-1) -> NaN, so
    // dist becomes NaN and d<=cutoff is false for any pair touching them.
    for (int q = (int)threadIdx.x; q < 3 * N; q += 256) {
        float v = coords[baseAtom * 3 + q];
        const int a = q / 3;
        const int c = q - 3 * a;
        if (species[baseAtom + a] == -1) v = __builtin_nanf("");
        l3[c][swz(a)] = v;
    }
    __syncthreads();

    const int p0 = (blockIdx.x * 256 + (int)threadIdx.x) * 4;
    if (p0 >= Psingle) return;

    const int M = 2 * N - 1;   // rowStart(i) = i*(M-i)/2

    // fp32 triangular inversion (exact: M*M < 2^24) + integer correction
    const float s = sqrtf((float)(M * M - 8 * p0));
    int i = (int)(((float)M - s) * 0.5f);
    if (i < 0) i = 0;
    if (i > N - 2) i = N - 2;
    while (i > 0 && p0 < (i * (M - i)) / 2) --i;
    while (p0 >= ((i + 1) * (M - i - 1)) / 2) ++i;

    int rs = (i * (M - i)) / 2;
    int re = rs + (N - 1 - i);

    float xi = l3[0][swz(i)];
    float yi = l3[1][swz(i)];
    float zi = l3[2][swz(i)];

    float vi0[4], vi1[4], vd[4], vdf[12];

#pragma unroll
    for (int k = 0; k < 4; ++k) {
        const int p = p0 + k;
        bool moved = false;
        while (p >= re) { ++i; rs = re; re += (N - 1 - i); moved = true; }
        if (moved) {
            xi = l3[0][swz(i)];
            yi = l3[1][swz(i)];
            zi = l3[2][swz(i)];
        }
        const int j  = p - rs + i + 1;
        const int sj = swz(j);

        const float dx = xi - l3[0][sj];
        const float dy = yi - l3[1][sj];
        const float dz = zi - l3[2][sj];
        const float d  = sqrtf(dx * dx + dy * dy + dz * dz);

        const bool valid = (d <= CUTOFF_F);   // false for NaN (dummy atoms)

        vi0[k] = valid ? (float)(baseAtom + i) : -1.0f;
        vi1[k] = valid ? (float)(baseAtom + j) : -1.0f;
        vd[k]  = valid ? d : 0.0f;
        vdf[3 * k + 0] = valid ? dx : 0.0f;
        vdf[3 * k + 1] = valid ? dy : 0.0f;
        vdf[3 * k + 2] = valid ? dz : 0.0f;
    }

    const int g0 = b * Psingle + p0;   // multiple of 4 -> 16B aligned

    float* __restrict__ ind0 = out;
    float* __restrict__ ind1 = out + Ptotal;
    float* __restrict__ dstp = out + 2 * (size_t)Ptotal;
    float* __restrict__ dfp  = out + 3 * (size_t)Ptotal;

    *(f4*)(ind0 + g0) = (f4){vi0[0], vi0[1], vi0[2], vi0[3]};
    *(f4*)(ind1 + g0) = (f4){vi1[0], vi1[1], vi1[2], vi1[3]};
    *(f4*)(dstp + g0) = (f4){vd[0],  vd[1],  vd[2],  vd[3]};

    f4* __restrict__ pdf = (f4*)(dfp + 3 * (size_t)g0);  // 48B/thread, aligned
    pdf[0] = (f4){vdf[0], vdf[1], vdf[2],  vdf[3]};
    pdf[1] = (f4){vdf[4], vdf[5], vdf[6],  vdf[7]};
    pdf[2] = (f4){vdf[8], vdf[9], vdf[10], vdf[11]};
}

extern "C" void kernel_launch(void* const* d_in, const int* in_sizes, int n_in,
                              void* d_out, int out_size, void* d_ws, size_t ws_size,
                              hipStream_t stream) {
    const int* species  = (const int*)d_in[0];   // [B, N] int32
    const float* coords = (const float*)d_in[1]; // [B, N, 3] float32

    const int S = in_sizes[0];                   // B*N
    // out_size = 3 * S * (N-1)  =>  N = out_size/(3*S) + 1
    const int N = out_size / (3 * S) + 1;
    const int B = S / N;
    const int Psingle = (N * (N - 1)) / 2;       // divisible by 4 for N=2048
    const int Ptotal  = B * Psingle;

    const int chunks = (Psingle + 3) / 4;
    dim3 grid((chunks + 255) / 256, B, 1);
    dim3 block(256, 1, 1);
    AllPairs_kernel<<<grid, block, 0, stream>>>(species, coords, (float*)d_out,
                                                N, Psingle, Ptotal);
}

// Round 5
// 394.894 us; speedup vs baseline: 1.1024x; 1.1024x over previous
//
#include <hip/hip_runtime.h>

#define CUTOFF_F 5.2f

typedef float f4 __attribute__((ext_vector_type(4)));

// Prepass: pack each atom as float4 {x,y,z,0} into d_ws; dummy atoms
// (species==-1) become NaN coords so any pair touching them fails d<=cutoff,
// exactly matching the reference's validity mask. Runs every launch (d_ws is
// re-poisoned by the harness).
__global__ __launch_bounds__(256) void AllPairs_prep(
    const int* __restrict__ species,
    const float* __restrict__ coords,
    f4* __restrict__ atoms, int total)
{
    const int a = blockIdx.x * 256 + (int)threadIdx.x;
    if (a >= total) return;
    float x = coords[3 * a + 0];
    float y = coords[3 * a + 1];
    float z = coords[3 * a + 2];
    if (species[a] == -1) { x = __builtin_nanf(""); y = x; z = x; }
    atoms[a] = (f4){x, y, z, 0.0f};
}

// Each thread handles 4 consecutive pairs of one batch's triangular pair list.
// Output layout (float32):
//   [0,   P) idx0 (-1 if invalid)   [P,  2P) idx1
//   [2P, 3P) dist (0 if invalid)    [3P, 6P) diff[P][3]
__global__ __launch_bounds__(256) void AllPairs_kernel(
    const f4* __restrict__ atoms,
    float* __restrict__ out,
    int N, int Psingle, int Ptotal)
{
    const int b  = blockIdx.y;
    const int p0 = (blockIdx.x * 256 + (int)threadIdx.x) * 4;
    if (p0 >= Psingle) return;

    const int M = 2 * N - 1;   // rowStart(i) = i*(M-i)/2

    // fp32 triangular inversion (exact: M*M < 2^24) + integer correction
    const float s = sqrtf((float)(M * M - 8 * p0));
    int i = (int)(((float)M - s) * 0.5f);
    if (i < 0) i = 0;
    if (i > N - 2) i = N - 2;
    while (i > 0 && p0 < (i * (M - i)) / 2) --i;
    while (p0 >= ((i + 1) * (M - i - 1)) / 2) ++i;

    int rs = (i * (M - i)) / 2;
    int re = rs + (N - 1 - i);

    const f4* __restrict__ ab = atoms + b * N;
    const int baseAtom = b * N;

    f4 ci = ab[i];

    float vi0[4], vi1[4], vd[4], vdf[12];

#pragma unroll
    for (int k = 0; k < 4; ++k) {
        const int p = p0 + k;
        while (p >= re) { ++i; rs = re; re += (N - 1 - i); ci = ab[i]; }
        const int j = p - rs + i + 1;
        const f4 cj = ab[j];          // one aligned 16B load per pair

        const float dx = ci.x - cj.x;
        const float dy = ci.y - cj.y;
        const float dz = ci.z - cj.z;
        const float d  = sqrtf(dx * dx + dy * dy + dz * dz);

        const bool valid = (d <= CUTOFF_F);   // false for NaN (dummy atoms)

        vi0[k] = valid ? (float)(baseAtom + i) : -1.0f;
        vi1[k] = valid ? (float)(baseAtom + j) : -1.0f;
        vd[k]  = valid ? d : 0.0f;
        vdf[3 * k + 0] = valid ? dx : 0.0f;
        vdf[3 * k + 1] = valid ? dy : 0.0f;
        vdf[3 * k + 2] = valid ? dz : 0.0f;
    }

    const int g0 = b * Psingle + p0;   // multiple of 4 -> 16B aligned

    float* __restrict__ ind0 = out;
    float* __restrict__ ind1 = out + Ptotal;
    float* __restrict__ dstp = out + 2 * (size_t)Ptotal;
    float* __restrict__ dfp  = out + 3 * (size_t)Ptotal;

    *(f4*)(ind0 + g0) = (f4){vi0[0], vi0[1], vi0[2], vi0[3]};
    *(f4*)(ind1 + g0) = (f4){vi1[0], vi1[1], vi1[2], vi1[3]};
    *(f4*)(dstp + g0) = (f4){vd[0],  vd[1],  vd[2],  vd[3]};

    f4* __restrict__ pdf = (f4*)(dfp + 3 * (size_t)g0);  // 48B/thread, aligned
    pdf[0] = (f4){vdf[0], vdf[1], vdf[2],  vdf[3]};
    pdf[1] = (f4){vdf[4], vdf[5], vdf[6],  vdf[7]};
    pdf[2] = (f4){vdf[8], vdf[9], vdf[10], vdf[11]};
}

extern "C" void kernel_launch(void* const* d_in, const int* in_sizes, int n_in,
                              void* d_out, int out_size, void* d_ws, size_t ws_size,
                              hipStream_t stream) {
    const int* species  = (const int*)d_in[0];   // [B, N] int32
    const float* coords = (const float*)d_in[1]; // [B, N, 3] float32

    const int S = in_sizes[0];                   // B*N
    // out_size = 3 * S * (N-1)  =>  N = out_size/(3*S) + 1
    const int N = out_size / (3 * S) + 1;
    const int B = S / N;
    const int Psingle = (N * (N - 1)) / 2;       // divisible by 4 for N=2048
    const int Ptotal  = B * Psingle;

    f4* atoms = (f4*)d_ws;                       // B*N*16 bytes (256 KB)

    AllPairs_prep<<<(S + 255) / 256, 256, 0, stream>>>(species, coords, atoms, S);

    const int chunks = (Psingle + 3) / 4;
    dim3 grid((chunks + 255) / 256, B, 1);
    dim3 block(256, 1, 1);
    AllPairs_kernel<<<grid, block, 0, stream>>>(atoms, (float*)d_out,
                                                N, Psingle, Ptotal);
}